// Round 16
// baseline (380.207 us; speedup 1.0000x reference)
//
#include <hip/hip_runtime.h>
#include <hip/hip_bf16.h>
#include <math.h>

#define NND 50000
#define NE 800000
#define NF 128
#define NH 64
#define NB 512
#define KP 30
#define NCLS 10
#define NBKT 49              // coarse buckets of 1024 dsts
#define NTILE 196            // edge tiles of 4096
#define NG1 782              // layer GEMM blocks (64 nodes each)
#define NSET 208             // setup blocks (208*256 = 53248)

typedef __hip_bfloat16 bf16;
typedef unsigned long long u64;
typedef unsigned short ushort_t;
typedef __attribute__((ext_vector_type(8))) short bf16x8;   // 8 bf16 (4 VGPRs)
typedef __attribute__((ext_vector_type(4))) float f32x4;

__device__ __forceinline__ float ldF(const void* p, size_t i, int isbf){
    return isbf ? __bfloat162float(((const bf16*)p)[i]) : ((const float*)p)[i];
}

// fp32 -> bf16 bits, round-to-nearest-even (matches HW/numpy)
__device__ __forceinline__ ushort_t f2bf(float v){
    unsigned u = __float_as_uint(v);
    unsigned r = u + 0x7FFFu + ((u >> 16) & 1u);
    return (ushort_t)(r >> 16);
}
__device__ __forceinline__ float bfLo(unsigned w){ return __uint_as_float(w << 16); }
__device__ __forceinline__ float bfHi(unsigned w){ return __uint_as_float(w & 0xFFFF0000u); }

// ---- wave-uniform dtype detection (no LDS, no barriers; all lanes active) ----
__device__ __forceinline__ int floatsAreBf16(const unsigned* __restrict__ xw, int tid){
    unsigned w = xw[tid & 63];
    int ex = (int)((w >> 7) & 0xFF);
    u64 m = __ballot(ex >= 100 && ex <= 140);
    return __popcll(m) >= 32;
}
__device__ __forceinline__ int intsAreI64(const int* __restrict__ ew, int tid){
    u64 m = __ballot(ew[2*(tid & 63) + 1] == 0);
    return __popcll(m) >= 48;
}

__device__ __forceinline__ int edgeSrc(const int* ei, int e, int i64){
    return i64 ? ei[2*e] : ei[e];
}
__device__ __forceinline__ int edgeDst(const int* ei, int e, int i64){
    return i64 ? ei[2*NE + 2*e] : ei[NE + e];
}

// ========== K1: bucket_count(+last-block scan fold) || setup ==========
__global__ __launch_bounds__(256) void k1_kernel(
    const unsigned* __restrict__ xw, const int* __restrict__ ei,
    const int* __restrict__ batch, int* __restrict__ starts,
    const void* W1l, const void* W1r, const void* b1,
    const void* W2l, const void* W2r, const void* b2,
    const void* W3l, const void* W3r, const void* b3,
    const void* convw, const void* convb,
    const void* l1w, const void* l1b, const void* l2w, const void* l2b,
    ushort_t* __restrict__ wB1, ushort_t* __restrict__ wB2, ushort_t* __restrict__ wB3,
    float* __restrict__ b1f, float* __restrict__ b2f, float* __restrict__ b3f,
    float* __restrict__ wT, float* __restrict__ cbf,
    float* __restrict__ l1wf, float* __restrict__ l1bf,
    float* __restrict__ l2wf, float* __restrict__ l2bf,
    int* __restrict__ bcnt, int* __restrict__ dctr,
    int* __restrict__ bbase, int* __restrict__ bcur, int* __restrict__ offs)
{
    int tid = threadIdx.x;
    if (blockIdx.x < NTILE){
        __shared__ int lh[NBKT];
        __shared__ int sc[NBKT];
        __shared__ int lastFlag;
        int i64 = intsAreI64(ei, tid);
        if (tid < NBKT) lh[tid] = 0;
        __syncthreads();
        int t0 = blockIdx.x*4096;
        #pragma unroll 4
        for (int k = 0; k < 16; ++k){
            int e = t0 + k*256 + tid;
            if (e < NE) atomicAdd(&lh[edgeDst(ei,e,i64) >> 10], 1);
        }
        __syncthreads();
        if (tid < NBKT && lh[tid]) atomicAdd(&bcnt[tid], lh[tid]);
        __syncthreads();
        if (tid == 0){
            __threadfence();
            int old = atomicAdd(dctr, 1);
            lastFlag = (old == NTILE-1) ? 1 : 0;
        }
        __syncthreads();
        if (lastFlag){
            if (tid < NBKT) sc[tid] = atomicAdd(&bcnt[tid], 0);
            __syncthreads();
            if (tid == 0){
                int acc = 0;
                for (int b = 0; b < NBKT; ++b){
                    bbase[b] = acc; bcur[b] = acc; acc += sc[b];
                }
                bbase[NBKT] = acc;
                offs[NND] = NE;
            }
        }
    } else {
        int wbf = floatsAreBf16(xw, tid);
        int i64 = intsAreI64(ei, tid);
        int i = (blockIdx.x - NTILE)*256 + tid;
        if (i < NND){
            int b  = i64 ? batch[2*i] : batch[i];
            int pb = (i == 0) ? -1 : (i64 ? batch[2*(i-1)] : batch[i-1]);
            for (int g = pb+1; g <= b; ++g) starts[g] = i;
            if (i == NND-1) for (int g = b+1; g <= NB; ++g) starts[g] = NND;
        }
        {
            int j = i & 7, lane = (i >> 3) & 63, t = (i >> 9) & 7, c = i >> 12;
            int k = c*32 + (lane >> 4)*8 + j;
            int n = t*16 + (lane & 15);
            if (i < 16384){
                float v = (n < 64) ? ldF(W1l, (size_t)k*NH + n, wbf)
                                   : ldF(W1r, (size_t)k*NH + (n-64), wbf);
                wB1[i] = f2bf(v);
            }
            if (i < 8192){
                float v2 = (n < 64) ? ldF(W2l, (size_t)k*NH + n, wbf)
                                    : ldF(W2r, (size_t)k*NH + (n-64), wbf);
                float v3 = (n < 64) ? ldF(W3l, (size_t)k*NH + n, wbf)
                                    : ldF(W3r, (size_t)k*NH + (n-64), wbf);
                wB2[i] = f2bf(v2);
                wB3[i] = f2bf(v3);
            }
        }
        if (i < 64){
            b1f[i] = ldF(b1, i, wbf);
            b2f[i] = ldF(b2, i, wbf);
            b3f[i] = ldF(b3, i, wbf);
            l1bf[i] = ldF(l1b, i, wbf);
        }
        if (i < 10240){
            int o = i / 320, rem = i - o*320, ch = rem/5, h = rem - ch*5;
            wT[ch*160 + h*32 + o] = ldF(convw, i, wbf);   // wT[ch][h][o]
        }
        if (i < 53248) l1wf[i] = ldF(l1w, i, wbf);
        if (i < 640)   l2wf[i] = ldF(l2w, i, wbf);
        if (i < 32)    cbf[i]  = ldF(convb, i, wbf);
        if (i < 10)    l2bf[i] = ldF(l2b, i, wbf);
    }
}

// ========== K2: layer-1 MFMA GEMM || bucket_scatter (independent) ==========
__global__ __launch_bounds__(256) void k2_kernel(
    const void* __restrict__ x, const int* __restrict__ ei,
    const ushort_t* __restrict__ wB1, const float* __restrict__ b1f,
    ushort_t* __restrict__ ybf, ushort_t* __restrict__ zb,
    int* __restrict__ bcur, int2* __restrict__ bedges)
{
    int tid = threadIdx.x;
    if (blockIdx.x < NG1){
        constexpr int K = NF, KC = K/32, RS = K + 8;
        __shared__ ushort_t hA[64*RS];
        int isbf = floatsAreBf16((const unsigned*)x, tid);
        int base = blockIdx.x * 64;
        for (int i = tid; i < 64*K; i += 256){
            int r = i / K, c = i - r*K;
            int node = base + r;
            float v = (node < NND) ? ldF(x, (size_t)node*K + c, isbf) : 0.f;
            hA[r*RS + c] = f2bf(v);
        }
        __syncthreads();
        int lane = tid & 63, w = tid >> 6;
        int n16 = lane & 15, quad = lane >> 4;
        f32x4 acc[8];
        #pragma unroll
        for (int t = 0; t < 8; ++t) acc[t] = (f32x4){0.f,0.f,0.f,0.f};
        const bf16x8* bp = (const bf16x8*)wB1;
        #pragma unroll
        for (int c = 0; c < KC; ++c){
            bf16x8 a = *(const bf16x8*)&hA[(w*16 + n16)*RS + c*32 + quad*8];
            #pragma unroll
            for (int t = 0; t < 8; ++t){
                bf16x8 b = bp[(c*8 + t)*64 + lane];
                acc[t] = __builtin_amdgcn_mfma_f32_16x16x32_bf16(a, b, acc[t], 0, 0, 0);
            }
        }
        #pragma unroll
        for (int t = 0; t < 8; ++t){
            int f = (t & 3)*16 + n16;
            float bv = (t >= 4) ? b1f[f] : 0.f;
            #pragma unroll
            for (int r = 0; r < 4; ++r){
                int node = base + w*16 + quad*4 + r;
                if (node < NND){
                    if (t < 4) ybf[(size_t)node*NH + f] = f2bf(acc[t][r]);
                    else       zb[(size_t)node*NH + f] = f2bf(acc[t][r] + bv);
                }
            }
        }
    } else {
        __shared__ int lh[NBKT];
        __shared__ int lcur[NBKT];
        int i64 = intsAreI64(ei, tid);
        if (tid < NBKT) lh[tid] = 0;
        __syncthreads();
        int t0 = (blockIdx.x - NG1)*4096;
        int myd[16], mys[16];
        int cnt = 0;
        #pragma unroll 4
        for (int k = 0; k < 16; ++k){
            int e = t0 + k*256 + tid;
            if (e < NE){
                int d = edgeDst(ei,e,i64), s_ = edgeSrc(ei,e,i64);
                myd[cnt] = d; mys[cnt] = s_; ++cnt;
                atomicAdd(&lh[d >> 10], 1);
            }
        }
        __syncthreads();
        if (tid < NBKT) lcur[tid] = lh[tid] ? atomicAdd(&bcur[tid], lh[tid]) : 0;
        __syncthreads();
        for (int k = 0; k < cnt; ++k){
            int b = myd[k] >> 10;
            int p = atomicAdd(&lcur[b], 1);
            bedges[p] = make_int2(mys[k], myd[k]);
        }
    }
}

__global__ __launch_bounds__(1024) void csr_finalize(const int2* __restrict__ bedges,
                                                     const int* __restrict__ bbase,
                                                     int* __restrict__ offs,
                                                     int* __restrict__ csr){
    __shared__ int hist[1024];
    int b = blockIdx.x;
    int tid = threadIdx.x;
    int dst0 = b << 10;
    int nd = NND - dst0; if (nd > 1024) nd = 1024;
    int e0 = bbase[b], e1 = bbase[b+1];
    hist[tid] = 0;
    __syncthreads();
    for (int e = e0 + tid; e < e1; e += 1024)
        atomicAdd(&hist[bedges[e].y - dst0], 1);
    __syncthreads();
    int own = hist[tid];
    for (int st = 1; st < 1024; st <<= 1){
        int v = (tid >= st) ? hist[tid-st] : 0;
        __syncthreads();
        hist[tid] += v;
        __syncthreads();
    }
    int excl = hist[tid] - own;
    if (tid < nd) offs[dst0 + tid] = e0 + excl;
    __syncthreads();
    hist[tid] = excl;
    __syncthreads();
    for (int e = e0 + tid; e < e1; e += 1024){
        int2 ed = bedges[e];
        int p = atomicAdd(&hist[ed.y - dst0], 1);
        csr[e0 + p] = ed.x;
    }
}

__device__ __forceinline__ void addbf8(uint4 u, float* a){
    a[0] += bfLo(u.x); a[1] += bfHi(u.x);
    a[2] += bfLo(u.y); a[3] += bfHi(u.y);
    a[4] += bfLo(u.z); a[5] += bfHi(u.z);
    a[6] += bfLo(u.w); a[7] += bfHi(u.w);
}
__device__ __forceinline__ void decbf8(uint4 u, float* o){
    o[0] = bfLo(u.x); o[1] = bfHi(u.x);
    o[2] = bfLo(u.y); o[3] = bfHi(u.y);
    o[4] = bfLo(u.z); o[5] = bfHi(u.z);
    o[6] = bfLo(u.w); o[7] = bfHi(u.w);
}

// ------ FUSED: h = relu(mean_csr(y)+z) -> LDS A-tile -> MFMA [y'|z'] (layers 2,3) ----
__global__ __launch_bounds__(256) void gather_mfma(
    const ushort_t* __restrict__ yb, const int* __restrict__ offs,
    const int* __restrict__ csr, const ushort_t* __restrict__ zb,
    const ushort_t* __restrict__ wB, const float* __restrict__ bfp,
    ushort_t* __restrict__ ybf_out, ushort_t* __restrict__ zb_out,
    ushort_t* __restrict__ ykey_out)
{
    constexpr int K = NH;
    constexpr int KC = K/32;
    constexpr int RS = K + 8;
    __shared__ ushort_t hA[64*RS];
    int tid = threadIdx.x;
    int base = blockIdx.x * 64;

    {   // phase A: gather+finalize 64 nodes into hA
        int nl = tid >> 2, q = tid & 3;
        int node = base + nl;
        float acc[16];
        #pragma unroll
        for (int i = 0; i < 16; ++i) acc[i] = 0.f;
        ushort_t row[16];
        if (node < NND){
            int o0 = offs[node], o1 = offs[node+1];
            int e = o0;
            for (; e + 3 < o1; e += 4){
                int s0 = csr[e], s1 = csr[e+1], s2 = csr[e+2], s3 = csr[e+3];
                const uint4* p0 = (const uint4*)&yb[(size_t)s0*NH + q*16];
                const uint4* p1 = (const uint4*)&yb[(size_t)s1*NH + q*16];
                const uint4* p2 = (const uint4*)&yb[(size_t)s2*NH + q*16];
                const uint4* p3 = (const uint4*)&yb[(size_t)s3*NH + q*16];
                uint4 a0 = p0[0], a1 = p0[1], b0 = p1[0], b1 = p1[1];
                uint4 c0 = p2[0], c1 = p2[1], d0 = p3[0], d1 = p3[1];
                addbf8(a0, acc); addbf8(a1, acc+8);
                addbf8(b0, acc); addbf8(b1, acc+8);
                addbf8(c0, acc); addbf8(c1, acc+8);
                addbf8(d0, acc); addbf8(d1, acc+8);
            }
            for (; e < o1; ++e){
                const uint4* p0 = (const uint4*)&yb[(size_t)csr[e]*NH + q*16];
                uint4 a0 = p0[0], a1 = p0[1];
                addbf8(a0, acc); addbf8(a1, acc+8);
            }
            float dd = (float)(o1 - o0); dd = dd > 1.f ? dd : 1.f;
            float inv = 1.f / dd;
            const uint4* zp = (const uint4*)&zb[(size_t)node*NH + q*16];
            uint4 zu0 = zp[0], zu1 = zp[1];
            float zf[16];
            decbf8(zu0, zf); decbf8(zu1, zf+8);
            #pragma unroll
            for (int i = 0; i < 16; ++i){
                float v = acc[i]*inv + zf[i];
                row[i] = f2bf(v > 0.f ? v : 0.f);
            }
        } else {
            #pragma unroll
            for (int i = 0; i < 16; ++i) row[i] = 0;
        }
        unsigned pk[8];
        #pragma unroll
        for (int i = 0; i < 8; ++i)
            pk[i] = (unsigned)row[2*i] | ((unsigned)row[2*i+1] << 16);
        *(uint4*)&hA[nl*RS + q*16]     = make_uint4(pk[0],pk[1],pk[2],pk[3]);
        *(uint4*)&hA[nl*RS + q*16 + 8] = make_uint4(pk[4],pk[5],pk[6],pk[7]);
    }
    __syncthreads();

    int lane = tid & 63, w = tid >> 6;
    int n16 = lane & 15, quad = lane >> 4;
    f32x4 acc[8];
    #pragma unroll
    for (int t = 0; t < 8; ++t) acc[t] = (f32x4){0.f,0.f,0.f,0.f};
    const bf16x8* bp = (const bf16x8*)wB;
    #pragma unroll
    for (int c = 0; c < KC; ++c){
        bf16x8 a = *(const bf16x8*)&hA[(w*16 + n16)*RS + c*32 + quad*8];
        #pragma unroll
        for (int t = 0; t < 8; ++t){
            bf16x8 b = bp[(c*8 + t)*64 + lane];
            acc[t] = __builtin_amdgcn_mfma_f32_16x16x32_bf16(a, b, acc[t], 0, 0, 0);
        }
    }
    #pragma unroll
    for (int t = 0; t < 8; ++t){
        int f = (t & 3)*16 + n16;
        float bv = (t >= 4) ? bfp[f] : 0.f;
        #pragma unroll
        for (int r = 0; r < 4; ++r){
            int node = base + w*16 + quad*4 + r;
            if (node < NND){
                if (t < 4){
                    ushort_t yv = f2bf(acc[t][r]);
                    ybf_out[(size_t)node*NH + f] = yv;
                    if (ykey_out != nullptr && t == 3 && n16 == 15)
                        ykey_out[node] = yv;          // compact y'[:,63]
                } else {
                    zb_out[(size_t)node*NH + f] = f2bf(acc[t][r] + bv);
                }
            }
        }
    }
}

__device__ __forceinline__ void acc4(uint2 u, float& a0, float& a1, float& a2, float& a3){
    a0 += bfLo(u.x); a1 += bfHi(u.x);
    a2 += bfLo(u.y); a3 += bfHi(u.y);
}

// ====== head v5: compact-key gather + bitonic top-30 + winner re-gather + conv(4grp)
//        + fc1 + fc2 + log_softmax.  LDS ~25KB (keys aliased into conv partials). ======
__global__ __launch_bounds__(256) void head5_kernel(
    const ushort_t* __restrict__ yb, const ushort_t* __restrict__ ykey,
    const int* __restrict__ offs, const int* __restrict__ csr,
    const ushort_t* __restrict__ zb, const int* __restrict__ starts,
    const float* __restrict__ wT, const float* __restrict__ cbf,
    const float* __restrict__ l1wf, const float* __restrict__ l1bf,
    const float* __restrict__ l2wf, const float* __restrict__ l2bf,
    float* __restrict__ outp)
{
    __shared__ double scratch8[1664];    // 13.3KB: keys (sort) ∪ part4 (conv partials)
    u64*   keys  = (u64*)scratch8;
    float* part4 = (float*)scratch8;
    __shared__ int  sel[32];
    __shared__ float pT[64*32];          // pT[ch][rank], ranks 30,31 zeroed
    __shared__ float cbuf[832];
    __shared__ float fbuf[NH];
    __shared__ float logitsS[NCLS];
    int g = blockIdx.x, tid = threadIdx.x;
    int s = starts[g], e = starts[g+1];
    int cnt = e - s; if (cnt > 256) cnt = 256; if (cnt < 0) cnt = 0;

    // ---- phase A: key from compact ykey (L2-resident 100KB; same order as gather) ----
    u64 key = 0xFFFFFFFFFFFFFFFFull;
    if (tid < cnt){
        int node = s + tid;
        int o0 = offs[node], o1 = offs[node+1];
        float a = 0.f;
        int ee = o0;
        for (; ee + 3 < o1; ee += 4){
            float v0 = bfLo((unsigned)ykey[csr[ee+0]]);
            float v1 = bfLo((unsigned)ykey[csr[ee+1]]);
            float v2 = bfLo((unsigned)ykey[csr[ee+2]]);
            float v3 = bfLo((unsigned)ykey[csr[ee+3]]);
            a += v0; a += v1; a += v2; a += v3;
        }
        for (; ee < o1; ++ee)
            a += bfLo((unsigned)ykey[csr[ee]]);
        float dd = (float)(o1 - o0); dd = dd > 1.f ? dd : 1.f;
        float inv = 1.f / dd;
        float v = a*inv + bfLo((unsigned)zb[(size_t)node*NH + 63]);
        v = v > 0.f ? v : 0.f;
        unsigned u = __float_as_uint(v);
        unsigned m = (u & 0x80000000u) ? ~u : (u | 0x80000000u);
        unsigned d = ~m;
        key = ((u64)d << 32) | (unsigned)tid;
    }
    keys[tid] = key;
    __syncthreads();
    for (int k = 2; k <= 256; k <<= 1){
        for (int j = k >> 1; j > 0; j >>= 1){
            int partner = tid ^ j;
            u64 a = keys[tid], b = keys[partner];
            bool up = ((tid & k) == 0);
            bool amin = a < b;
            u64 keep;
            if (partner > tid) keep = (up == amin) ? a : b;
            else               keep = (up == amin) ? b : a;
            __syncthreads();
            keys[tid] = keep;
            __syncthreads();
        }
    }
    if (tid < KP){
        u64 kk = keys[tid];
        sel[tid] = ((unsigned)(kk >> 32) == 0xFFFFFFFFu) ? -1 : (int)(kk & 0xFFFFFFFFu);
    }
    if (tid < 64){ pT[tid*32 + 30] = 0.f; pT[tid*32 + 31] = 0.f; }
    __syncthreads();

    // ---- phase B: full-row re-gather for the 30 winners -> pT ----
    #pragma unroll
    for (int r0 = 0; r0 < 32; r0 += 16){
        int r = r0 + (tid >> 4);
        int q = tid & 15;
        if (r < KP){
            float4 v = make_float4(0.f,0.f,0.f,0.f);
            int li = sel[r];
            if (li >= 0){
                int node = s + li;
                int o0 = offs[node], o1 = offs[node+1];
                float a0=0.f, a1=0.f, a2=0.f, a3=0.f;
                int ee = o0;
                for (; ee + 3 < o1; ee += 4){
                    int s0 = csr[ee], s1 = csr[ee+1], s2 = csr[ee+2], s3 = csr[ee+3];
                    uint2 u0 = *(const uint2*)&yb[(size_t)s0*NH + q*4];
                    uint2 u1 = *(const uint2*)&yb[(size_t)s1*NH + q*4];
                    uint2 u2 = *(const uint2*)&yb[(size_t)s2*NH + q*4];
                    uint2 u3 = *(const uint2*)&yb[(size_t)s3*NH + q*4];
                    acc4(u0, a0,a1,a2,a3); acc4(u1, a0,a1,a2,a3);
                    acc4(u2, a0,a1,a2,a3); acc4(u3, a0,a1,a2,a3);
                }
                for (; ee < o1; ++ee){
                    uint2 u = *(const uint2*)&yb[(size_t)csr[ee]*NH + q*4];
                    acc4(u, a0,a1,a2,a3);
                }
                float dd = (float)(o1 - o0); dd = dd > 1.f ? dd : 1.f;
                float inv = 1.f / dd;
                uint2 zu = *(const uint2*)&zb[(size_t)node*NH + q*4];
                v.x = a0*inv + bfLo(zu.x); v.y = a1*inv + bfHi(zu.x);
                v.z = a2*inv + bfLo(zu.y); v.w = a3*inv + bfHi(zu.y);
                v.x = v.x > 0.f ? v.x : 0.f;  v.y = v.y > 0.f ? v.y : 0.f;
                v.z = v.z > 0.f ? v.z : 0.f;  v.w = v.w > 0.f ? v.w : 0.f;
            }
            pT[(q*4+0)*32 + r] = v.x;
            pT[(q*4+1)*32 + r] = v.y;
            pT[(q*4+2)*32 + r] = v.z;
            pT[(q*4+3)*32 + r] = v.w;
        }
    }
    __syncthreads();

    // ---- conv1d: 4 groups of 64 lanes (o = lane&31, t-half = lane>>5), 13 t each ----
    {
        int lane = tid & 63, chg4 = tid >> 6;
        int o = lane & 31, th = lane >> 5;
        int t0 = th ? 13 : 0;
        int f4s = th ? 3 : 0;            // float4 window start in pT row
        int poff = th ? 1 : 0;           // p[] local offset: (t0+tl+h) - 4*f4s
        float acc[13];
        #pragma unroll
        for (int t = 0; t < 13; ++t) acc[t] = 0.f;
        for (int c16 = 0; c16 < 16; ++c16){
            int ch = chg4*16 + c16;
            const float4* prow = (const float4*)&pT[ch*32];
            float p[20];
            #pragma unroll
            for (int j = 0; j < 5; ++j){
                float4 v = prow[f4s + j];
                p[4*j]=v.x; p[4*j+1]=v.y; p[4*j+2]=v.z; p[4*j+3]=v.w;
            }
            const float* wrow = &wT[ch*160 + o];
            #pragma unroll
            for (int h = 0; h < 5; ++h){
                float wv = wrow[h*32];
                #pragma unroll
                for (int t = 0; t < 13; ++t) acc[t] += p[t+h+poff]*wv;
            }
        }
        #pragma unroll
        for (int t = 0; t < 13; ++t)
            part4[chg4*832 + o*26 + t0 + t] = acc[t];
    }
    __syncthreads();

    for (int i = tid; i < 832; i += 256){
        int oo = i / 26;
        float a = cbf[oo] + part4[i] + part4[832+i] + part4[2*832+i] + part4[3*832+i];
        cbuf[i] = a > 0.f ? a : 0.f;
    }
    __syncthreads();

    {   // fc1: 832 -> 64 (partials reuse part4[0..255])
        int p = tid >> 6, j = tid & 63;
        float a = 0.f;
        int m0 = p*208;
        #pragma unroll 4
        for (int m = m0; m < m0 + 208; ++m)
            a += cbuf[m] * l1wf[(size_t)m*NH + j];
        part4[p*NH + j] = a;
    }
    __syncthreads();
    if (tid < NH){
        float v = part4[tid] + part4[NH+tid] + part4[2*NH+tid] + part4[3*NH+tid] + l1bf[tid];
        fbuf[tid] = v > 0.f ? v : 0.f;
    }
    __syncthreads();
    if (tid < NCLS){
        float a = l2bf[tid];
        #pragma unroll
        for (int j = 0; j < NH; ++j) a += fbuf[j] * l2wf[j*NCLS + tid];
        logitsS[tid] = a;
    }
    __syncthreads();
    if (tid == 0){
        float m = logitsS[0];
        for (int c = 1; c < NCLS; ++c) m = fmaxf(m, logitsS[c]);
        float ssum = 0.f;
        for (int c = 0; c < NCLS; ++c) ssum += expf(logitsS[c]-m);
        float lse = m + logf(ssum);
        for (int c = 0; c < NCLS; ++c)
            outp[(size_t)g*NCLS + c] = logitsS[c] - lse;
    }
}

extern "C" void kernel_launch(void* const* d_in, const int* in_sizes, int n_in,
                              void* d_out, int out_size, void* d_ws, size_t ws_size,
                              hipStream_t stream) {
    const void* x    = d_in[0];
    const int*  ei   = (const int*)d_in[1];
    const int*  batch= (const int*)d_in[2];
    const void *W1l=d_in[3], *b1=d_in[4],  *W1r=d_in[5];
    const void *W2l=d_in[6], *b2=d_in[7],  *W2r=d_in[8];
    const void *W3l=d_in[9], *b3=d_in[10], *W3r=d_in[11];
    const void *convw=d_in[12], *convb=d_in[13];
    const void *l1w=d_in[14], *l1b=d_in[15];
    const void *l2w=d_in[16], *l2b=d_in[17];
    float* out = (float*)d_out;

    float* wsf = (float*)d_ws;
    ushort_t* yA = (ushort_t*)wsf;                        // NND*64 bf16
    ushort_t* zA = yA + (size_t)NND*NH;                   // NND*64 bf16
    ushort_t* yB = zA + (size_t)NND*NH;                   // NND*64 bf16
    ushort_t* zB = yB + (size_t)NND*NH;                   // NND*64 bf16
    int2* bedges = (int2*)(zB + (size_t)NND*NH);          // NE int2 (8B-aligned)
    ushort_t* wB1 = (ushort_t*)(bedges + NE);             // 16384
    ushort_t* wB2 = wB1 + 16384;                          // 8192
    ushort_t* wB3 = wB2 + 8192;                           // 8192
    ushort_t* ykey = wB3 + 8192;                          // NND (compact y3[:,63])
    float* b1f  = (float*)(ykey + NND + 8);               // 64
    float* b2f  = b1f + 64;
    float* b3f  = b2f + 64;
    float* wT   = b3f + 64;                               // 10240
    float* cbf  = wT + 10240;                             // 32
    float* l1wf = cbf + 32;                               // 53248
    float* l1bf = l1wf + 53248;                           // 64
    float* l2wf = l1bf + 64;                              // 640
    float* l2bf = l2wf + 640;                             // 10 (+pad)
    int* starts = (int*)(l2bf + 16);                      // 513
    int* bcnt   = starts + 520;                           // 49
    int* dctr   = bcnt + NBKT;                            // 1 (contiguous w/ bcnt)
    int* bbase  = bcnt + 64;                              // 50
    int* bcur   = bbase + 64;                             // 49
    int* offs   = bcur + 64;                              // 50001
    int* csr    = offs + NND + 3;                         // 800000

    // zero bcnt[49] + dctr (contiguous 50 ints)
    (void)hipMemsetAsync(bcnt, 0, 50*sizeof(int), stream);

    // K1: count(+scan fold) || setup
    k1_kernel<<<NTILE + NSET, 256, 0, stream>>>(
        (const unsigned*)x, ei, batch, starts,
        W1l, W1r, b1, W2l, W2r, b2, W3l, W3r, b3,
        convw, convb, l1w, l1b, l2w, l2b,
        wB1, wB2, wB3, b1f, b2f, b3f,
        wT, cbf, l1wf, l1bf, l2wf, l2bf,
        bcnt, dctr, bbase, bcur, offs);

    // K2: layer-1 GEMM || bucket_scatter
    k2_kernel<<<NG1 + NTILE, 256, 0, stream>>>(
        x, ei, wB1, b1f, yA, zA, bcur, bedges);

    // K3: per-bucket fine CSR
    csr_finalize<<<NBKT, 1024, 0, stream>>>(bedges, bbase, offs, csr);

    // K4/K5: fused gather+GEMM layers 2 and 3 (K5 also emits compact ykey)
    gather_mfma<<<NG1, 256, 0, stream>>>(yA, offs, csr, zA, wB2, b2f, yB, zB, nullptr);
    gather_mfma<<<NG1, 256, 0, stream>>>(yB, offs, csr, zB, wB3, b3f, yA, zA, ykey);

    // K6: fused final-gather + sort-pool + conv + MLP + log_softmax
    head5_kernel<<<NB, 256, 0, stream>>>(yA, ykey, offs, csr, zA, starts,
                                         wT, cbf, l1wf, l1bf, l2wf, l2bf, out);
}

// Round 17
// 263.570 us; speedup vs baseline: 1.4425x; 1.4425x over previous
//
#include <hip/hip_runtime.h>
#include <hip/hip_bf16.h>
#include <math.h>

#define NND 50000
#define NE 800000
#define NF 128
#define NH 64
#define NB 512
#define KP 30
#define NCLS 10
#define NBKT 49              // coarse buckets of 1024 dsts
#define NTILE 196            // edge tiles of 4096
#define NG1 782              // layer GEMM blocks (64 nodes each)
#define NSET 208             // setup blocks (208*256 = 53248)

typedef __hip_bfloat16 bf16;
typedef unsigned long long u64;
typedef unsigned short ushort_t;
typedef __attribute__((ext_vector_type(8))) short bf16x8;   // 8 bf16 (4 VGPRs)
typedef __attribute__((ext_vector_type(4))) float f32x4;

__device__ __forceinline__ float ldF(const void* p, size_t i, int isbf){
    return isbf ? __bfloat162float(((const bf16*)p)[i]) : ((const float*)p)[i];
}

// fp32 -> bf16 bits, round-to-nearest-even (matches HW/numpy)
__device__ __forceinline__ ushort_t f2bf(float v){
    unsigned u = __float_as_uint(v);
    unsigned r = u + 0x7FFFu + ((u >> 16) & 1u);
    return (ushort_t)(r >> 16);
}
__device__ __forceinline__ float bfLo(unsigned w){ return __uint_as_float(w << 16); }
__device__ __forceinline__ float bfHi(unsigned w){ return __uint_as_float(w & 0xFFFF0000u); }

// ---- wave-uniform dtype detection (no LDS, no barriers; all lanes active) ----
__device__ __forceinline__ int floatsAreBf16(const unsigned* __restrict__ xw, int tid){
    unsigned w = xw[tid & 63];
    int ex = (int)((w >> 7) & 0xFF);
    u64 m = __ballot(ex >= 100 && ex <= 140);
    return __popcll(m) >= 32;
}
__device__ __forceinline__ int intsAreI64(const int* __restrict__ ew, int tid){
    u64 m = __ballot(ew[2*(tid & 63) + 1] == 0);
    return __popcll(m) >= 48;
}

__device__ __forceinline__ int edgeSrc(const int* ei, int e, int i64){
    return i64 ? ei[2*e] : ei[e];
}
__device__ __forceinline__ int edgeDst(const int* ei, int e, int i64){
    return i64 ? ei[2*NE + 2*e] : ei[NE + e];
}

// ========== K1: bucket_count(+last-block scan fold) || setup ==========
__global__ __launch_bounds__(256) void k1_kernel(
    const unsigned* __restrict__ xw, const int* __restrict__ ei,
    const int* __restrict__ batch, int* __restrict__ starts,
    const void* W1l, const void* W1r, const void* b1,
    const void* W2l, const void* W2r, const void* b2,
    const void* W3l, const void* W3r, const void* b3,
    const void* convw, const void* convb,
    const void* l1w, const void* l1b, const void* l2w, const void* l2b,
    ushort_t* __restrict__ wB1, ushort_t* __restrict__ wB2, ushort_t* __restrict__ wB3,
    float* __restrict__ b1f, float* __restrict__ b2f, float* __restrict__ b3f,
    float* __restrict__ wT, float* __restrict__ cbf,
    float* __restrict__ l1wf, float* __restrict__ l1bf,
    float* __restrict__ l2wf, float* __restrict__ l2bf,
    int* __restrict__ bcnt, int* __restrict__ dctr,
    int* __restrict__ bbase, int* __restrict__ bcur, int* __restrict__ offs)
{
    int tid = threadIdx.x;
    if (blockIdx.x < NTILE){
        __shared__ int lh[NBKT];
        __shared__ int sc[NBKT];
        __shared__ int lastFlag;
        int i64 = intsAreI64(ei, tid);
        if (tid < NBKT) lh[tid] = 0;
        __syncthreads();
        int t0 = blockIdx.x*4096;
        #pragma unroll 4
        for (int k = 0; k < 16; ++k){
            int e = t0 + k*256 + tid;
            if (e < NE) atomicAdd(&lh[edgeDst(ei,e,i64) >> 10], 1);
        }
        __syncthreads();
        if (tid < NBKT && lh[tid]) atomicAdd(&bcnt[tid], lh[tid]);
        __syncthreads();
        if (tid == 0){
            __threadfence();
            int old = atomicAdd(dctr, 1);
            lastFlag = (old == NTILE-1) ? 1 : 0;
        }
        __syncthreads();
        if (lastFlag){
            if (tid < NBKT) sc[tid] = atomicAdd(&bcnt[tid], 0);
            __syncthreads();
            if (tid == 0){
                int acc = 0;
                for (int b = 0; b < NBKT; ++b){
                    bbase[b] = acc; bcur[b] = acc; acc += sc[b];
                }
                bbase[NBKT] = acc;
                offs[NND] = NE;
            }
        }
    } else {
        int wbf = floatsAreBf16(xw, tid);
        int i64 = intsAreI64(ei, tid);
        int i = (blockIdx.x - NTILE)*256 + tid;
        if (i < NND){
            int b  = i64 ? batch[2*i] : batch[i];
            int pb = (i == 0) ? -1 : (i64 ? batch[2*(i-1)] : batch[i-1]);
            for (int g = pb+1; g <= b; ++g) starts[g] = i;
            if (i == NND-1) for (int g = b+1; g <= NB; ++g) starts[g] = NND;
        }
        {
            int j = i & 7, lane = (i >> 3) & 63, t = (i >> 9) & 7, c = i >> 12;
            int k = c*32 + (lane >> 4)*8 + j;
            int n = t*16 + (lane & 15);
            if (i < 16384){
                float v = (n < 64) ? ldF(W1l, (size_t)k*NH + n, wbf)
                                   : ldF(W1r, (size_t)k*NH + (n-64), wbf);
                wB1[i] = f2bf(v);
            }
            if (i < 8192){
                float v2 = (n < 64) ? ldF(W2l, (size_t)k*NH + n, wbf)
                                    : ldF(W2r, (size_t)k*NH + (n-64), wbf);
                float v3 = (n < 64) ? ldF(W3l, (size_t)k*NH + n, wbf)
                                    : ldF(W3r, (size_t)k*NH + (n-64), wbf);
                wB2[i] = f2bf(v2);
                wB3[i] = f2bf(v3);
            }
        }
        if (i < 64){
            b1f[i] = ldF(b1, i, wbf);
            b2f[i] = ldF(b2, i, wbf);
            b3f[i] = ldF(b3, i, wbf);
            l1bf[i] = ldF(l1b, i, wbf);
        }
        if (i < 10240){
            int o = i / 320, rem = i - o*320, ch = rem/5, h = rem - ch*5;
            wT[ch*160 + h*32 + o] = ldF(convw, i, wbf);   // wT[ch][h][o]
        }
        if (i < 53248) l1wf[i] = ldF(l1w, i, wbf);
        if (i < 640)   l2wf[i] = ldF(l2w, i, wbf);
        if (i < 32)    cbf[i]  = ldF(convb, i, wbf);
        if (i < 10)    l2bf[i] = ldF(l2b, i, wbf);
    }
}

// ========== K2: layer-1 MFMA GEMM || bucket_scatter (independent) ==========
__global__ __launch_bounds__(256) void k2_kernel(
    const void* __restrict__ x, const int* __restrict__ ei,
    const ushort_t* __restrict__ wB1, const float* __restrict__ b1f,
    ushort_t* __restrict__ ybf, ushort_t* __restrict__ zb,
    int* __restrict__ bcur, int2* __restrict__ bedges)
{
    int tid = threadIdx.x;
    if (blockIdx.x < NG1){
        constexpr int K = NF, KC = K/32, RS = K + 8;
        __shared__ ushort_t hA[64*RS];
        int isbf = floatsAreBf16((const unsigned*)x, tid);
        int base = blockIdx.x * 64;
        for (int i = tid; i < 64*K; i += 256){
            int r = i / K, c = i - r*K;
            int node = base + r;
            float v = (node < NND) ? ldF(x, (size_t)node*K + c, isbf) : 0.f;
            hA[r*RS + c] = f2bf(v);
        }
        __syncthreads();
        int lane = tid & 63, w = tid >> 6;
        int n16 = lane & 15, quad = lane >> 4;
        f32x4 acc[8];
        #pragma unroll
        for (int t = 0; t < 8; ++t) acc[t] = (f32x4){0.f,0.f,0.f,0.f};
        const bf16x8* bp = (const bf16x8*)wB1;
        #pragma unroll
        for (int c = 0; c < KC; ++c){
            bf16x8 a = *(const bf16x8*)&hA[(w*16 + n16)*RS + c*32 + quad*8];
            #pragma unroll
            for (int t = 0; t < 8; ++t){
                bf16x8 b = bp[(c*8 + t)*64 + lane];
                acc[t] = __builtin_amdgcn_mfma_f32_16x16x32_bf16(a, b, acc[t], 0, 0, 0);
            }
        }
        #pragma unroll
        for (int t = 0; t < 8; ++t){
            int f = (t & 3)*16 + n16;
            float bv = (t >= 4) ? b1f[f] : 0.f;
            #pragma unroll
            for (int r = 0; r < 4; ++r){
                int node = base + w*16 + quad*4 + r;
                if (node < NND){
                    if (t < 4) ybf[(size_t)node*NH + f] = f2bf(acc[t][r]);
                    else       zb[(size_t)node*NH + f] = f2bf(acc[t][r] + bv);
                }
            }
        }
    } else {
        __shared__ int lh[NBKT];
        __shared__ int lcur[NBKT];
        int i64 = intsAreI64(ei, tid);
        if (tid < NBKT) lh[tid] = 0;
        __syncthreads();
        int t0 = (blockIdx.x - NG1)*4096;
        int myd[16], mys[16];
        int cnt = 0;
        #pragma unroll 4
        for (int k = 0; k < 16; ++k){
            int e = t0 + k*256 + tid;
            if (e < NE){
                int d = edgeDst(ei,e,i64), s_ = edgeSrc(ei,e,i64);
                myd[cnt] = d; mys[cnt] = s_; ++cnt;
                atomicAdd(&lh[d >> 10], 1);
            }
        }
        __syncthreads();
        if (tid < NBKT) lcur[tid] = lh[tid] ? atomicAdd(&bcur[tid], lh[tid]) : 0;
        __syncthreads();
        for (int k = 0; k < cnt; ++k){
            int b = myd[k] >> 10;
            int p = atomicAdd(&lcur[b], 1);
            bedges[p] = make_int2(mys[k], myd[k]);
        }
    }
}

__global__ __launch_bounds__(1024) void csr_finalize(const int2* __restrict__ bedges,
                                                     const int* __restrict__ bbase,
                                                     int* __restrict__ offs,
                                                     int* __restrict__ csr){
    __shared__ int hist[1024];
    int b = blockIdx.x;
    int tid = threadIdx.x;
    int dst0 = b << 10;
    int nd = NND - dst0; if (nd > 1024) nd = 1024;
    int e0 = bbase[b], e1 = bbase[b+1];
    hist[tid] = 0;
    __syncthreads();
    for (int e = e0 + tid; e < e1; e += 1024)
        atomicAdd(&hist[bedges[e].y - dst0], 1);
    __syncthreads();
    int own = hist[tid];
    for (int st = 1; st < 1024; st <<= 1){
        int v = (tid >= st) ? hist[tid-st] : 0;
        __syncthreads();
        hist[tid] += v;
        __syncthreads();
    }
    int excl = hist[tid] - own;
    if (tid < nd) offs[dst0 + tid] = e0 + excl;
    __syncthreads();
    hist[tid] = excl;
    __syncthreads();
    for (int e = e0 + tid; e < e1; e += 1024){
        int2 ed = bedges[e];
        int p = atomicAdd(&hist[ed.y - dst0], 1);
        csr[e0 + p] = ed.x;
    }
}

__device__ __forceinline__ void addbf8(uint4 u, float* a){
    a[0] += bfLo(u.x); a[1] += bfHi(u.x);
    a[2] += bfLo(u.y); a[3] += bfHi(u.y);
    a[4] += bfLo(u.z); a[5] += bfHi(u.z);
    a[6] += bfLo(u.w); a[7] += bfHi(u.w);
}
__device__ __forceinline__ void decbf8(uint4 u, float* o){
    o[0] = bfLo(u.x); o[1] = bfHi(u.x);
    o[2] = bfLo(u.y); o[3] = bfHi(u.y);
    o[4] = bfLo(u.z); o[5] = bfHi(u.z);
    o[6] = bfLo(u.w); o[7] = bfHi(u.w);
}

// ------ FUSED: h = relu(mean_csr(y)+z) -> LDS A-tile -> MFMA [y'|z'] (layers 2,3) ----
__global__ __launch_bounds__(256) void gather_mfma(
    const ushort_t* __restrict__ yb, const int* __restrict__ offs,
    const int* __restrict__ csr, const ushort_t* __restrict__ zb,
    const ushort_t* __restrict__ wB, const float* __restrict__ bfp,
    ushort_t* __restrict__ ybf_out, ushort_t* __restrict__ zb_out,
    ushort_t* __restrict__ ykey_out)
{
    constexpr int K = NH;
    constexpr int KC = K/32;
    constexpr int RS = K + 8;
    __shared__ ushort_t hA[64*RS];
    int tid = threadIdx.x;
    int base = blockIdx.x * 64;

    {   // phase A: gather+finalize 64 nodes into hA
        int nl = tid >> 2, q = tid & 3;
        int node = base + nl;
        float acc[16];
        #pragma unroll
        for (int i = 0; i < 16; ++i) acc[i] = 0.f;
        ushort_t row[16];
        if (node < NND){
            int o0 = offs[node], o1 = offs[node+1];
            int e = o0;
            for (; e + 3 < o1; e += 4){
                int s0 = csr[e], s1 = csr[e+1], s2 = csr[e+2], s3 = csr[e+3];
                const uint4* p0 = (const uint4*)&yb[(size_t)s0*NH + q*16];
                const uint4* p1 = (const uint4*)&yb[(size_t)s1*NH + q*16];
                const uint4* p2 = (const uint4*)&yb[(size_t)s2*NH + q*16];
                const uint4* p3 = (const uint4*)&yb[(size_t)s3*NH + q*16];
                uint4 a0 = p0[0], a1 = p0[1], b0 = p1[0], b1 = p1[1];
                uint4 c0 = p2[0], c1 = p2[1], d0 = p3[0], d1 = p3[1];
                addbf8(a0, acc); addbf8(a1, acc+8);
                addbf8(b0, acc); addbf8(b1, acc+8);
                addbf8(c0, acc); addbf8(c1, acc+8);
                addbf8(d0, acc); addbf8(d1, acc+8);
            }
            for (; e < o1; ++e){
                const uint4* p0 = (const uint4*)&yb[(size_t)csr[e]*NH + q*16];
                uint4 a0 = p0[0], a1 = p0[1];
                addbf8(a0, acc); addbf8(a1, acc+8);
            }
            float dd = (float)(o1 - o0); dd = dd > 1.f ? dd : 1.f;
            float inv = 1.f / dd;
            const uint4* zp = (const uint4*)&zb[(size_t)node*NH + q*16];
            uint4 zu0 = zp[0], zu1 = zp[1];
            float zf[16];
            decbf8(zu0, zf); decbf8(zu1, zf+8);
            #pragma unroll
            for (int i = 0; i < 16; ++i){
                float v = acc[i]*inv + zf[i];
                row[i] = f2bf(v > 0.f ? v : 0.f);
            }
        } else {
            #pragma unroll
            for (int i = 0; i < 16; ++i) row[i] = 0;
        }
        unsigned pk[8];
        #pragma unroll
        for (int i = 0; i < 8; ++i)
            pk[i] = (unsigned)row[2*i] | ((unsigned)row[2*i+1] << 16);
        *(uint4*)&hA[nl*RS + q*16]     = make_uint4(pk[0],pk[1],pk[2],pk[3]);
        *(uint4*)&hA[nl*RS + q*16 + 8] = make_uint4(pk[4],pk[5],pk[6],pk[7]);
    }
    __syncthreads();

    int lane = tid & 63, w = tid >> 6;
    int n16 = lane & 15, quad = lane >> 4;
    f32x4 acc[8];
    #pragma unroll
    for (int t = 0; t < 8; ++t) acc[t] = (f32x4){0.f,0.f,0.f,0.f};
    const bf16x8* bp = (const bf16x8*)wB;
    #pragma unroll
    for (int c = 0; c < KC; ++c){
        bf16x8 a = *(const bf16x8*)&hA[(w*16 + n16)*RS + c*32 + quad*8];
        #pragma unroll
        for (int t = 0; t < 8; ++t){
            bf16x8 b = bp[(c*8 + t)*64 + lane];
            acc[t] = __builtin_amdgcn_mfma_f32_16x16x32_bf16(a, b, acc[t], 0, 0, 0);
        }
    }
    #pragma unroll
    for (int t = 0; t < 8; ++t){
        int f = (t & 3)*16 + n16;
        float bv = (t >= 4) ? bfp[f] : 0.f;
        #pragma unroll
        for (int r = 0; r < 4; ++r){
            int node = base + w*16 + quad*4 + r;
            if (node < NND){
                if (t < 4){
                    ushort_t yv = f2bf(acc[t][r]);
                    ybf_out[(size_t)node*NH + f] = yv;
                    if (ykey_out != nullptr && t == 3 && n16 == 15)
                        ykey_out[node] = yv;          // compact y'[:,63]
                } else {
                    zb_out[(size_t)node*NH + f] = f2bf(acc[t][r] + bv);
                }
            }
        }
    }
}

__device__ __forceinline__ void acc4(uint2 u, float& a0, float& a1, float& a2, float& a3){
    a0 += bfLo(u.x); a1 += bfHi(u.x);
    a2 += bfLo(u.y); a3 += bfHi(u.y);
}

// ====== head v6: compact-key gather + bitonic top-30 + winner re-gather +
//        conv (8 groups, compile-time indices — R16 lesson: NO runtime-variable
//        private-array indexing) + fc1 + fc2 + log_softmax. keys aliased in part. ======
__global__ __launch_bounds__(256) void head6_kernel(
    const ushort_t* __restrict__ yb, const ushort_t* __restrict__ ykey,
    const int* __restrict__ offs, const int* __restrict__ csr,
    const ushort_t* __restrict__ zb, const int* __restrict__ starts,
    const float* __restrict__ wT, const float* __restrict__ cbf,
    const float* __restrict__ l1wf, const float* __restrict__ l1bf,
    const float* __restrict__ l2wf, const float* __restrict__ l2bf,
    float* __restrict__ outp)
{
    __shared__ double scratch8[3328];    // 26.6KB: keys(2KB, sort) ∪ part[8*832] (conv)
    u64*   keys = (u64*)scratch8;
    float* part = (float*)scratch8;
    __shared__ int  sel[32];
    __shared__ float pT[64*32];          // pT[ch][rank], ranks 30,31 zeroed
    __shared__ float cbuf[832];
    __shared__ float fbuf[NH];
    __shared__ float logitsS[NCLS];
    int g = blockIdx.x, tid = threadIdx.x;
    int s = starts[g], e = starts[g+1];
    int cnt = e - s; if (cnt > 256) cnt = 256; if (cnt < 0) cnt = 0;

    // ---- phase A: key from compact ykey (L2-resident 100KB; same order as gather) ----
    u64 key = 0xFFFFFFFFFFFFFFFFull;
    if (tid < cnt){
        int node = s + tid;
        int o0 = offs[node], o1 = offs[node+1];
        float a = 0.f;
        int ee = o0;
        for (; ee + 3 < o1; ee += 4){
            float v0 = bfLo((unsigned)ykey[csr[ee+0]]);
            float v1 = bfLo((unsigned)ykey[csr[ee+1]]);
            float v2 = bfLo((unsigned)ykey[csr[ee+2]]);
            float v3 = bfLo((unsigned)ykey[csr[ee+3]]);
            a += v0; a += v1; a += v2; a += v3;
        }
        for (; ee < o1; ++ee)
            a += bfLo((unsigned)ykey[csr[ee]]);
        float dd = (float)(o1 - o0); dd = dd > 1.f ? dd : 1.f;
        float inv = 1.f / dd;
        float v = a*inv + bfLo((unsigned)zb[(size_t)node*NH + 63]);
        v = v > 0.f ? v : 0.f;
        unsigned u = __float_as_uint(v);
        unsigned m = (u & 0x80000000u) ? ~u : (u | 0x80000000u);
        unsigned d = ~m;
        key = ((u64)d << 32) | (unsigned)tid;
    }
    keys[tid] = key;
    __syncthreads();
    for (int k = 2; k <= 256; k <<= 1){
        for (int j = k >> 1; j > 0; j >>= 1){
            int partner = tid ^ j;
            u64 a = keys[tid], b = keys[partner];
            bool up = ((tid & k) == 0);
            bool amin = a < b;
            u64 keep;
            if (partner > tid) keep = (up == amin) ? a : b;
            else               keep = (up == amin) ? b : a;
            __syncthreads();
            keys[tid] = keep;
            __syncthreads();
        }
    }
    if (tid < KP){
        u64 kk = keys[tid];
        sel[tid] = ((unsigned)(kk >> 32) == 0xFFFFFFFFu) ? -1 : (int)(kk & 0xFFFFFFFFu);
    }
    if (tid < 64){ pT[tid*32 + 30] = 0.f; pT[tid*32 + 31] = 0.f; }
    __syncthreads();

    // ---- phase B: full-row re-gather for the 30 winners -> pT ----
    #pragma unroll
    for (int r0 = 0; r0 < 32; r0 += 16){
        int r = r0 + (tid >> 4);
        int q = tid & 15;
        if (r < KP){
            float4 v = make_float4(0.f,0.f,0.f,0.f);
            int li = sel[r];
            if (li >= 0){
                int node = s + li;
                int o0 = offs[node], o1 = offs[node+1];
                float a0=0.f, a1=0.f, a2=0.f, a3=0.f;
                int ee = o0;
                for (; ee + 3 < o1; ee += 4){
                    int s0 = csr[ee], s1 = csr[ee+1], s2 = csr[ee+2], s3 = csr[ee+3];
                    uint2 u0 = *(const uint2*)&yb[(size_t)s0*NH + q*4];
                    uint2 u1 = *(const uint2*)&yb[(size_t)s1*NH + q*4];
                    uint2 u2 = *(const uint2*)&yb[(size_t)s2*NH + q*4];
                    uint2 u3 = *(const uint2*)&yb[(size_t)s3*NH + q*4];
                    acc4(u0, a0,a1,a2,a3); acc4(u1, a0,a1,a2,a3);
                    acc4(u2, a0,a1,a2,a3); acc4(u3, a0,a1,a2,a3);
                }
                for (; ee < o1; ++ee){
                    uint2 u = *(const uint2*)&yb[(size_t)csr[ee]*NH + q*4];
                    acc4(u, a0,a1,a2,a3);
                }
                float dd = (float)(o1 - o0); dd = dd > 1.f ? dd : 1.f;
                float inv = 1.f / dd;
                uint2 zu = *(const uint2*)&zb[(size_t)node*NH + q*4];
                v.x = a0*inv + bfLo(zu.x); v.y = a1*inv + bfHi(zu.x);
                v.z = a2*inv + bfLo(zu.y); v.w = a3*inv + bfHi(zu.y);
                v.x = v.x > 0.f ? v.x : 0.f;  v.y = v.y > 0.f ? v.y : 0.f;
                v.z = v.z > 0.f ? v.z : 0.f;  v.w = v.w > 0.f ? v.w : 0.f;
            }
            pT[(q*4+0)*32 + r] = v.x;
            pT[(q*4+1)*32 + r] = v.y;
            pT[(q*4+2)*32 + r] = v.z;
            pT[(q*4+3)*32 + r] = v.w;
        }
    }
    __syncthreads();

    // ---- conv1d: 8 groups, all private-array indices compile-time constant ----
    {
        int o = tid & 31, chg = tid >> 5;
        float acc[26];
        #pragma unroll
        for (int t = 0; t < 26; ++t) acc[t] = 0.f;
        for (int c8 = 0; c8 < 8; ++c8){
            int ch = chg*8 + c8;
            const float4* prow = (const float4*)&pT[ch*32];
            float p[32];
            #pragma unroll
            for (int q = 0; q < 8; ++q){
                float4 v = prow[q];
                p[4*q]=v.x; p[4*q+1]=v.y; p[4*q+2]=v.z; p[4*q+3]=v.w;
            }
            const float* wrow = &wT[ch*160 + o];
            #pragma unroll
            for (int h = 0; h < 5; ++h){
                float wv = wrow[h*32];
                #pragma unroll
                for (int t = 0; t < 26; ++t) acc[t] += p[t+h]*wv;
            }
        }
        #pragma unroll
        for (int t = 0; t < 26; ++t) part[chg*832 + o*26 + t] = acc[t];
    }
    __syncthreads();

    for (int i = tid; i < 832; i += 256){
        int oo = i / 26;
        float a = cbf[oo];
        #pragma unroll
        for (int cg = 0; cg < 8; ++cg) a += part[cg*832 + i];
        cbuf[i] = a > 0.f ? a : 0.f;
    }
    __syncthreads();

    {   // fc1: 832 -> 64 (partials reuse part[0..255])
        int p = tid >> 6, j = tid & 63;
        float a = 0.f;
        int m0 = p*208;
        #pragma unroll 4
        for (int m = m0; m < m0 + 208; ++m)
            a += cbuf[m] * l1wf[(size_t)m*NH + j];
        part[p*NH + j] = a;
    }
    __syncthreads();
    if (tid < NH){
        float v = part[tid] + part[NH+tid] + part[2*NH+tid] + part[3*NH+tid] + l1bf[tid];
        fbuf[tid] = v > 0.f ? v : 0.f;
    }
    __syncthreads();
    if (tid < NCLS){
        float a = l2bf[tid];
        #pragma unroll
        for (int j = 0; j < NH; ++j) a += fbuf[j] * l2wf[j*NCLS + tid];
        logitsS[tid] = a;
    }
    __syncthreads();
    if (tid == 0){
        float m = logitsS[0];
        for (int c = 1; c < NCLS; ++c) m = fmaxf(m, logitsS[c]);
        float ssum = 0.f;
        for (int c = 0; c < NCLS; ++c) ssum += expf(logitsS[c]-m);
        float lse = m + logf(ssum);
        for (int c = 0; c < NCLS; ++c)
            outp[(size_t)g*NCLS + c] = logitsS[c] - lse;
    }
}

extern "C" void kernel_launch(void* const* d_in, const int* in_sizes, int n_in,
                              void* d_out, int out_size, void* d_ws, size_t ws_size,
                              hipStream_t stream) {
    const void* x    = d_in[0];
    const int*  ei   = (const int*)d_in[1];
    const int*  batch= (const int*)d_in[2];
    const void *W1l=d_in[3], *b1=d_in[4],  *W1r=d_in[5];
    const void *W2l=d_in[6], *b2=d_in[7],  *W2r=d_in[8];
    const void *W3l=d_in[9], *b3=d_in[10], *W3r=d_in[11];
    const void *convw=d_in[12], *convb=d_in[13];
    const void *l1w=d_in[14], *l1b=d_in[15];
    const void *l2w=d_in[16], *l2b=d_in[17];
    float* out = (float*)d_out;

    float* wsf = (float*)d_ws;
    ushort_t* yA = (ushort_t*)wsf;                        // NND*64 bf16
    ushort_t* zA = yA + (size_t)NND*NH;                   // NND*64 bf16
    ushort_t* yB = zA + (size_t)NND*NH;                   // NND*64 bf16
    ushort_t* zB = yB + (size_t)NND*NH;                   // NND*64 bf16
    int2* bedges = (int2*)(zB + (size_t)NND*NH);          // NE int2 (8B-aligned)
    ushort_t* wB1 = (ushort_t*)(bedges + NE);             // 16384
    ushort_t* wB2 = wB1 + 16384;                          // 8192
    ushort_t* wB3 = wB2 + 8192;                           // 8192
    ushort_t* ykey = wB3 + 8192;                          // NND (compact y3[:,63])
    float* b1f  = (float*)(ykey + NND + 8);               // 64
    float* b2f  = b1f + 64;
    float* b3f  = b2f + 64;
    float* wT   = b3f + 64;                               // 10240
    float* cbf  = wT + 10240;                             // 32
    float* l1wf = cbf + 32;                               // 53248
    float* l1bf = l1wf + 53248;                           // 64
    float* l2wf = l1bf + 64;                              // 640
    float* l2bf = l2wf + 640;                             // 10 (+pad)
    int* starts = (int*)(l2bf + 16);                      // 513
    int* bcnt   = starts + 520;                           // 49
    int* dctr   = bcnt + NBKT;                            // 1 (contiguous w/ bcnt)
    int* bbase  = bcnt + 64;                              // 50
    int* bcur   = bbase + 64;                             // 49
    int* offs   = bcur + 64;                              // 50001
    int* csr    = offs + NND + 3;                         // 800000

    // zero bcnt[49] + dctr (contiguous 50 ints)
    (void)hipMemsetAsync(bcnt, 0, 50*sizeof(int), stream);

    // K1: count(+scan fold) || setup
    k1_kernel<<<NTILE + NSET, 256, 0, stream>>>(
        (const unsigned*)x, ei, batch, starts,
        W1l, W1r, b1, W2l, W2r, b2, W3l, W3r, b3,
        convw, convb, l1w, l1b, l2w, l2b,
        wB1, wB2, wB3, b1f, b2f, b3f,
        wT, cbf, l1wf, l1bf, l2wf, l2bf,
        bcnt, dctr, bbase, bcur, offs);

    // K2: layer-1 GEMM || bucket_scatter
    k2_kernel<<<NG1 + NTILE, 256, 0, stream>>>(
        x, ei, wB1, b1f, yA, zA, bcur, bedges);

    // K3: per-bucket fine CSR
    csr_finalize<<<NBKT, 1024, 0, stream>>>(bedges, bbase, offs, csr);

    // K4/K5: fused gather+GEMM layers 2 and 3 (K5 also emits compact ykey)
    gather_mfma<<<NG1, 256, 0, stream>>>(yA, offs, csr, zA, wB2, b2f, yB, zB, nullptr);
    gather_mfma<<<NG1, 256, 0, stream>>>(yB, offs, csr, zB, wB3, b3f, yA, zA, ykey);

    // K6: fused final-gather + sort-pool + conv + MLP + log_softmax
    head6_kernel<<<NB, 256, 0, stream>>>(yA, ykey, offs, csr, zA, starts,
                                         wT, cbf, l1wf, l1bf, l2wf, l2bf, out);
}